// Round 1
// baseline (262.149 us; speedup 1.0000x reference)
//
#include <hip/hip_runtime.h>
#include <stdint.h>

#define HID 2048
#define NH  32
#define HD  64
#define NB  8
#define NS  16
#define PAST 4096

// log2(e) / sqrt(D) = 1.4426950408889634 / 8
#define QSCALE 0.18033688011112042591f

typedef __attribute__((ext_vector_type(8))) short short8;
typedef __attribute__((ext_vector_type(4))) short short4v;
typedef __attribute__((ext_vector_type(4))) float f32x4;

#define MFMA(a, b, c) __builtin_amdgcn_mfma_f32_16x16x32_bf16((a), (b), (c), 0, 0, 0)

static __device__ __forceinline__ short f2bf(float f) {
    union { float f; uint32_t u; } v; v.f = f;
    uint32_t r = (v.u + 0x7FFFu + ((v.u >> 16) & 1u)) >> 16;
    return (short)r;
}

static __device__ __forceinline__ short8 pack8(float4 a, float4 b) {
    short8 r;
    r[0] = f2bf(a.x); r[1] = f2bf(a.y); r[2] = f2bf(a.z); r[3] = f2bf(a.w);
    r[4] = f2bf(b.x); r[5] = f2bf(b.y); r[6] = f2bf(b.z); r[7] = f2bf(b.w);
    return r;
}

static __device__ __forceinline__ short8 pack8s(float4 a, float4 b, float s) {
    short8 r;
    r[0] = f2bf(a.x * s); r[1] = f2bf(a.y * s); r[2] = f2bf(a.z * s); r[3] = f2bf(a.w * s);
    r[4] = f2bf(b.x * s); r[5] = f2bf(b.y * s); r[6] = f2bf(b.z * s); r[7] = f2bf(b.w * s);
    return r;
}

// ---------------- hidden fp32 -> bf16 ----------------
__global__ __launch_bounds__(256) void cvt_kernel(const float* __restrict__ in,
                                                  short* __restrict__ out) {
    int i = (blockIdx.x * 256 + threadIdx.x) * 4;
    float4 v = *reinterpret_cast<const float4*>(in + i);
    short4v o;
    o[0] = f2bf(v.x); o[1] = f2bf(v.y); o[2] = f2bf(v.z); o[3] = f2bf(v.w);
    *reinterpret_cast<short4v*>(out + i) = o;
}

// ---------------- Y = Xbf16 @ W^T  (M=128, K=2048), N=16 per block --------
// grid: nMats*128 blocks of 256 threads. mat = blockIdx.x>>7.
__global__ __launch_bounds__(256) void proj_kernel(
        const short* __restrict__ X,
        const float* __restrict__ W0, const float* __restrict__ W1,
        const float* __restrict__ W2,
        float* __restrict__ Y0, float* __restrict__ Y1, float* __restrict__ Y2) {
    int mat   = blockIdx.x >> 7;
    int nbase = (blockIdx.x & 127) * 16;
    const float* W = (mat == 0) ? W0 : (mat == 1) ? W1 : W2;
    float*       Y = (mat == 0) ? Y0 : (mat == 1) ? Y1 : Y2;

    int lane = threadIdx.x & 63;
    int wave = threadIdx.x >> 6;
    int lr = lane & 15, g = lane >> 4;

    f32x4 acc0 = {0.f, 0.f, 0.f, 0.f};
    f32x4 acc1 = {0.f, 0.f, 0.f, 0.f};

    const short* xr0 = X + (size_t)(wave * 32 + lr) * HID + g * 8;
    const short* xr1 = X + (size_t)(wave * 32 + 16 + lr) * HID + g * 8;
    const float* wr  = W + (size_t)(nbase + lr) * HID + g * 8;

    for (int kc = 0; kc < HID; kc += 32) {
        short8 a0 = *reinterpret_cast<const short8*>(xr0 + kc);
        short8 a1 = *reinterpret_cast<const short8*>(xr1 + kc);
        float4 w0 = *reinterpret_cast<const float4*>(wr + kc);
        float4 w1 = *reinterpret_cast<const float4*>(wr + kc + 4);
        short8 b = pack8(w0, w1);
        acc0 = MFMA(a0, b, acc0);
        acc1 = MFMA(a1, b, acc1);
    }
    #pragma unroll
    for (int r = 0; r < 4; ++r) {
        Y[(size_t)(wave * 32 + g * 4 + r) * HID + nbase + lr]      = acc0[r];
        Y[(size_t)(wave * 32 + 16 + g * 4 + r) * HID + nbase + lr] = acc1[r];
    }
}

// ---------------- fused attention, one block per (b,h) -------------------
__global__ __launch_bounds__(1024) void attn_kernel(
        const float* __restrict__ q,
        const float* __restrict__ knew, const float* __restrict__ vnew,
        const float* __restrict__ pastK, const float* __restrict__ pastV,
        short* __restrict__ attn_out) {
    int bx = blockIdx.x;            // b*32 + h
    int b = bx >> 5, h = bx & 31;
    int tid  = threadIdx.x;
    int wave = tid >> 6, lane = tid & 63;
    int lq = lane & 15, g = lane >> 4;

    // Q fragments (B operand of swapped QK^T), pre-scaled by log2(e)/8
    const float* qp = q + (size_t)(b * NS + lq) * HID + h * HD + g * 8;
    short8 qf0, qf1;
    {
        float4 a0 = *reinterpret_cast<const float4*>(qp);
        float4 a1 = *reinterpret_cast<const float4*>(qp + 4);
        float4 a2 = *reinterpret_cast<const float4*>(qp + 32);
        float4 a3 = *reinterpret_cast<const float4*>(qp + 36);
        qf0 = pack8s(a0, a1, QSCALE);
        qf1 = pack8s(a2, a3, QSCALE);
    }

    f32x4 o[4];
    #pragma unroll
    for (int i = 0; i < 4; ++i) o[i] = (f32x4){0.f, 0.f, 0.f, 0.f};
    float m = -__builtin_inff(), lsum = 0.0f;

    const float* kb = pastK + (size_t)bx * PAST * HD;
    const float* vb = pastV + (size_t)bx * PAST * HD;

    for (int t = 0; t < 4; ++t) {
        int pb = wave * 256 + t * 64;

        // ---- scores: S^T[pos][q] via mfma(K_tile, Q) ----
        f32x4 sc[4];
        #pragma unroll
        for (int s2 = 0; s2 < 4; ++s2) {
            const float* kr = kb + (size_t)(pb + s2 * 16 + lq) * HD + g * 8;
            float4 k0 = *reinterpret_cast<const float4*>(kr);
            float4 k1 = *reinterpret_cast<const float4*>(kr + 4);
            float4 k2 = *reinterpret_cast<const float4*>(kr + 32);
            float4 k3 = *reinterpret_cast<const float4*>(kr + 36);
            short8 af0 = pack8(k0, k1);
            short8 af1 = pack8(k2, k3);
            f32x4 s = {0.f, 0.f, 0.f, 0.f};
            s = MFMA(af0, qf0, s);
            s = MFMA(af1, qf1, s);
            sc[s2] = s;
        }

        // ---- online softmax (per query = lane&15, partners l^16, l^32) ----
        float tmax = -__builtin_inff();
        #pragma unroll
        for (int s2 = 0; s2 < 4; ++s2)
            #pragma unroll
            for (int r = 0; r < 4; ++r) tmax = fmaxf(tmax, sc[s2][r]);
        tmax = fmaxf(tmax, __shfl_xor(tmax, 16));
        tmax = fmaxf(tmax, __shfl_xor(tmax, 32));
        float mn = fmaxf(m, tmax);
        float alpha = exp2f(m - mn);
        float p[16];
        float rsum = 0.f;
        #pragma unroll
        for (int i = 0; i < 16; ++i) {
            p[i] = exp2f(sc[i >> 2][i & 3] - mn);
            rsum += p[i];
        }
        rsum += __shfl_xor(rsum, 16);
        rsum += __shfl_xor(rsum, 32);
        lsum = lsum * alpha + rsum;
        m = mn;
        #pragma unroll
        for (int i = 0; i < 4; ++i) o[i] = o[i] * alpha;

        short8 pf0, pf1;
        #pragma unroll
        for (int j = 0; j < 8; ++j) { pf0[j] = f2bf(p[j]); pf1[j] = f2bf(p[8 + j]); }

        // ---- PV: O^T[d][q] += V^T frags x P^T ----
        const float* vt = vb + (size_t)pb * HD;
        #pragma unroll
        for (int dt = 0; dt < 4; ++dt) {
            int dcol = dt * 16 + lq;
            #pragma unroll
            for (int kf = 0; kf < 2; ++kf) {
                short8 vf;
                #pragma unroll
                for (int j = 0; j < 8; ++j) {
                    int pos = kf * 32 + ((j >> 2) << 4) + (g << 2) + (j & 3);
                    vf[j] = f2bf(vt[(size_t)pos * HD + dcol]);
                }
                o[dt] = MFMA(vf, kf ? pf1 : pf0, o[dt]);
            }
        }
    }

    // ---- the 16 new tokens (wave 0 only) ----
    if (wave == 0) {
        const float* kr = knew + (size_t)(b * NS + lq) * HID + h * HD + g * 8;
        float4 k0 = *reinterpret_cast<const float4*>(kr);
        float4 k1 = *reinterpret_cast<const float4*>(kr + 4);
        float4 k2 = *reinterpret_cast<const float4*>(kr + 32);
        float4 k3 = *reinterpret_cast<const float4*>(kr + 36);
        short8 af0 = pack8(k0, k1);
        short8 af1 = pack8(k2, k3);
        f32x4 s = {0.f, 0.f, 0.f, 0.f};
        s = MFMA(af0, qf0, s);
        s = MFMA(af1, qf1, s);

        float tmax = fmaxf(fmaxf(s[0], s[1]), fmaxf(s[2], s[3]));
        tmax = fmaxf(tmax, __shfl_xor(tmax, 16));
        tmax = fmaxf(tmax, __shfl_xor(tmax, 32));
        float mn = fmaxf(m, tmax);
        float alpha = exp2f(m - mn);
        float p4[4];
        float rsum = 0.f;
        #pragma unroll
        for (int r = 0; r < 4; ++r) { p4[r] = exp2f(s[r] - mn); rsum += p4[r]; }
        rsum += __shfl_xor(rsum, 16);
        rsum += __shfl_xor(rsum, 32);
        lsum = lsum * alpha + rsum;
        m = mn;
        #pragma unroll
        for (int i = 0; i < 4; ++i) o[i] = o[i] * alpha;

        short8 pf;
        #pragma unroll
        for (int j = 0; j < 4; ++j) pf[j] = f2bf(p4[j]);
        #pragma unroll
        for (int j = 4; j < 8; ++j) pf[j] = 0;

        #pragma unroll
        for (int dt = 0; dt < 4; ++dt) {
            int dcol = dt * 16 + lq;
            short8 vf;
            #pragma unroll
            for (int j = 0; j < 4; ++j) {
                int pos = (g << 2) + (j & 3);
                vf[j] = f2bf(vnew[(size_t)(b * NS + pos) * HID + h * HD + dcol]);
            }
            #pragma unroll
            for (int j = 4; j < 8; ++j) vf[j] = 0;
            o[dt] = MFMA(vf, pf, o[dt]);
        }
    }

    // ---- merge the 16 wave-partials via LDS ----
    __shared__ float s_o[16][16][64];
    __shared__ float s_m[16][16];
    __shared__ float s_l[16][16];
    #pragma unroll
    for (int dt = 0; dt < 4; ++dt)
        #pragma unroll
        for (int r = 0; r < 4; ++r)
            s_o[wave][lq][dt * 16 + g * 4 + r] = o[dt][r];
    if (g == 0) { s_m[wave][lq] = m; s_l[wave][lq] = lsum; }
    __syncthreads();

    if (wave == 0) {
        float M = -__builtin_inff();
        #pragma unroll
        for (int w = 0; w < 16; ++w) M = fmaxf(M, s_m[w][lq]);
        float aw[16];
        float L = 0.f;
        #pragma unroll
        for (int w = 0; w < 16; ++w) {
            aw[w] = exp2f(s_m[w][lq] - M);
            L += aw[w] * s_l[w][lq];
        }
        float inv = 1.0f / L;
        short* op = attn_out + (size_t)(b * NS + lq) * HID + h * HD + g * 16;
        #pragma unroll
        for (int dd = 0; dd < 16; ++dd) {
            float v = 0.f;
            #pragma unroll
            for (int w = 0; w < 16; ++w) v += s_o[w][lq][g * 16 + dd] * aw[w];
            op[dd] = f2bf(v * inv);
        }
    }
}

extern "C" void kernel_launch(void* const* d_in, const int* in_sizes, int n_in,
                              void* d_out, int out_size, void* d_ws, size_t ws_size,
                              hipStream_t stream) {
    const float* hs     = (const float*)d_in[0];
    const float* past_k = (const float*)d_in[1];
    const float* past_v = (const float*)d_in[2];
    const float* wq     = (const float*)d_in[3];
    const float* wk     = (const float*)d_in[4];
    const float* wv     = (const float*)d_in[5];
    const float* wo     = (const float*)d_in[6];
    float* out = (float*)d_out;

    float* qb = (float*)d_ws;                 // 128x2048 f32
    float* kn = qb + 128 * 2048;              // 128x2048 f32
    float* vn = kn + 128 * 2048;              // 128x2048 f32
    short* hsb   = (short*)(vn + 128 * 2048); // 128x2048 bf16
    short* attnb = hsb + 128 * 2048;          // 128x2048 bf16

    cvt_kernel<<<256, 256, 0, stream>>>(hs, hsb);
    proj_kernel<<<384, 256, 0, stream>>>(hsb, wq, wk, wv, qb, kn, vn);
    attn_kernel<<<256, 1024, 0, stream>>>(qb, kn, vn, past_k, past_v, attnb);
    proj_kernel<<<128, 256, 0, stream>>>(attnb, wo, wo, wo, out, out, out);
}